// Round 6
// baseline (91.489 us; speedup 1.0000x reference)
//
#include <hip/hip_runtime.h>

#define N_ROWS 4096
#define D_K    2048
#define BM 256
#define BK 32
#define NT (D_K / BK)   // 64 K-tiles
#define MARGIN 0.3f

typedef unsigned short u16;
typedef __attribute__((ext_vector_type(8))) short bf16x8;
typedef __attribute__((ext_vector_type(4))) float f32x4;

__device__ __forceinline__ void stage16(const u16* src, u16* dst) {
    __builtin_amdgcn_global_load_lds((const __attribute__((address_space(1))) unsigned int*)src,
                                     (__attribute__((address_space(3))) unsigned int*)dst, 16, 0, 0);
}

__device__ __forceinline__ u16 f2bf(float f) {
    unsigned u = __float_as_uint(f);
    u += 0x7fffu + ((u >> 16) & 1u);   // round-to-nearest-even
    return (u16)(u >> 16);
}

// ---------- Kernel 1: fp32 -> bf16 convert, exact fp32 row norms, init ap2/an2 ----------
__global__ __launch_bounds__(256) void prep_kernel(
    const float* __restrict__ emb, u16* __restrict__ embB,
    float* __restrict__ xx, unsigned* __restrict__ ap2, unsigned* __restrict__ an2)
{
    const int row = blockIdx.x;
    const int t = threadIdx.x;
    const float4* src = (const float4*)(emb + (size_t)row * D_K);
    ushort4* dst = (ushort4*)(embB + (size_t)row * D_K);
    float s = 0.f;
#pragma unroll
    for (int i = 0; i < 2; ++i) {
        float4 v = src[t + i * 256];
        s = fmaf(v.x, v.x, s);
        s = fmaf(v.y, v.y, s);
        s = fmaf(v.z, v.z, s);
        s = fmaf(v.w, v.w, s);
        ushort4 o;
        o.x = f2bf(v.x); o.y = f2bf(v.y); o.z = f2bf(v.z); o.w = f2bf(v.w);
        dst[t + i * 256] = o;
    }
#pragma unroll
    for (int off = 32; off >= 1; off >>= 1) s += __shfl_down(s, off, 64);
    __shared__ float red[4];
    if ((t & 63) == 0) red[t >> 6] = s;
    __syncthreads();
    if (t == 0) {
        xx[row] = red[0] + red[1] + red[2] + red[3];
        ap2[row] = 0u;            // float 0.0
        an2[row] = 0x7f7fffffu;   // FLT_MAX
    }
}

// ---------- Kernel 2: 256^2, BK=32, triple-buffered, 1 barrier/K-tile ----------
#define LDv(p) (*(const bf16x8*)(p))
#define BARRIER()  __builtin_amdgcn_s_barrier()
#define VMW_(n)    asm volatile("s_waitcnt vmcnt(" #n ")" ::: "memory")
#define VMW(n)     VMW_(n)

// Stage one full K-tile (A: 2 ops of 128 rows, B: 2 ops) into buffer B3_ (literal 0/1/2).
#define STAGE32(B3_, KTE_) do {                       \
    stage16(gA0 + (KTE_), lA + (B3_) * 8192);         \
    stage16(gA1 + (KTE_), lA + (B3_) * 8192 + 4096);  \
    stage16(gB0 + (KTE_), lB + (B3_) * 8192);         \
    stage16(gB1 + (KTE_), lB + (B3_) * 8192 + 4096);  \
} while (0)

// One K-tile: B_ = buf (LITERAL, = T_%3), T_ = tile index (runtime ok).
// Stage tile T_+2 into buf (B_+2)%3; one barrier; counted VMW(4) leaves stage(T_+2) in flight.
#define KT32(B_, T_)                                                                  \
  {                                                                                   \
    const bool ok = ((T_) + 2 < NT);                                                  \
    if (ok) { STAGE32(((B_) + 2) % 3, ((T_) + 2) * BK); }                             \
    bf16x8 aq[8], bq[4];                                                              \
    _Pragma("unroll")                                                                 \
    for (int n = 0; n < 4; ++n)                                                       \
        bq[n] = LDv(BB + (B_) * 16384 + bOff + n * 1024 + kx);                        \
    _Pragma("unroll")                                                                 \
    for (int m = 0; m < 8; ++m)                                                       \
        aq[m] = LDv(AB + (B_) * 16384 + aOff + m * 1024 + kx);                        \
    __builtin_amdgcn_s_setprio(1);                                                    \
    _Pragma("unroll")                                                                 \
    for (int m = 0; m < 8; ++m)                                                       \
        _Pragma("unroll")                                                             \
        for (int n = 0; n < 4; ++n)                                                   \
            acc[m][n] = __builtin_amdgcn_mfma_f32_16x16x32_bf16(aq[m], bq[n], acc[m][n], 0, 0, 0); \
    __builtin_amdgcn_s_setprio(0);                                                    \
    if (ok) { VMW(4); } else { VMW(0); }                                              \
    BARRIER();                                                                        \
  }

__global__ __launch_bounds__(512, 2) void gram_reduce_kernel(
    const u16* __restrict__ embB, const float* __restrict__ xx,
    const int* __restrict__ lab, unsigned* __restrict__ ap2, unsigned* __restrict__ an2)
{
    __shared__ u16 Ash[3 * BM * BK];   // 48 KiB: [buf][256 rows][32 cols], swizzled 16B slots
    __shared__ u16 Bsh[3 * BM * BK];   // 48 KiB
    __shared__ int labR[BM], labC[BM];
    __shared__ float xxR[BM], xxC[BM];

    const int tid = threadIdx.x;
    const int bid = blockIdx.x;
    const int swz = (bid & 7) * 32 + (bid >> 3);   // bijective: 256 % 8 == 0
    const int bm = swz >> 4, bn = swz & 15;
    const int row0 = bm * BM, col0 = bn * BM;

    // ---- staging: linear LDS dest (base + tid*16B), pre-swizzled global source.
    // Row = 64B = 4 slots of 16B; involution: slot ^= row&3.
    const int csw = ((tid & 3) ^ ((tid >> 2) & 3)) * 8;   // in u16 elements
    const int srow = tid >> 2;                            // 0..127
    const u16* gA0 = embB + (size_t)(row0 + srow) * D_K + csw;
    const u16* gA1 = embB + (size_t)(row0 + 128 + srow) * D_K + csw;
    const u16* gB0 = embB + (size_t)(col0 + srow) * D_K + csw;
    const u16* gB1 = embB + (size_t)(col0 + 128 + srow) * D_K + csw;
    u16* lA = Ash + tid * 8;
    u16* lB = Bsh + tid * 8;

    // ---- fragment-read constants
    const int l = tid & 63, w = tid >> 6;
    const int wr = w >> 2, wc = w & 3;          // 2 x 4 wave grid, per-wave 128x64
    const int fr = l & 15, fkb = l >> 4;        // frag row / k-slot (0..3)
    const int kx = ((fkb ^ (fr & 3)) * 16);     // swizzled k-offset bytes within 64B row
    const char* AB = (const char*)Ash;
    const char* BB = (const char*)Bsh;
    const int aOff = wr * 8192 + fr * 64;                             // + buf*16384 + m*1024
    const int bOff = (wc >> 1) * 8192 + (wc & 1) * 4096 + fr * 64;    // + buf*16384 + n*1024

    f32x4 acc[8][4];
#pragma unroll
    for (int m = 0; m < 8; ++m)
#pragma unroll
        for (int n = 0; n < 4; ++n) acc[m][n] = (f32x4){0.f, 0.f, 0.f, 0.f};

    // ---- prologue: tile 0 -> buf0, tile 1 -> buf1; publish tile 0, leave tile 1 in flight
    STAGE32(0, 0);
    STAGE32(1, BK);
    VMW(4);
    BARRIER();

    // ---- main loop: 3 K-tiles per iteration (buf = tile%3 as literal); tail tile 63
    for (int ii = 0; ii < 21; ++ii) {
        const int t3 = 3 * ii;
        KT32(0, t3)
        KT32(1, t3 + 1)
        KT32(2, t3 + 2)
    }
    KT32(0, 63)

    // ---- epilogue metadata (only needed here)
    if (tid < 256) { labR[tid] = lab[row0 + tid]; xxR[tid] = xx[row0 + tid]; }
    else           { int u2 = tid - 256; labC[u2] = lab[col0 + u2]; xxC[u2] = xx[col0 + u2]; }
    __syncthreads();

    // ---- epilogue: d2 = xx_i + xx_j - 2g, clamp, masked max/min, 16-lane reduce, atomics
    const int rgrp = l >> 4;
#pragma unroll
    for (int m = 0; m < 8; ++m) {
#pragma unroll
        for (int r = 0; r < 4; ++r) {
            const int il = wr * 128 + m * 16 + rgrp * 4 + r;   // C/D row = (lane>>4)*4 + reg
            const int li = labR[il];
            const float xi = xxR[il];
            float apv = 0.f, anv = __FLT_MAX__;
#pragma unroll
            for (int n = 0; n < 4; ++n) {
                const int jl = wc * 64 + n * 16 + fr;          // C/D col = lane&15
                float d2 = xi + xxC[jl] - 2.f * acc[m][n][r];
                d2 = fmaxf(d2, 1e-12f);
                const bool same = (labC[jl] == li);
                apv = same ? fmaxf(apv, d2) : apv;
                anv = same ? anv : fminf(anv, d2);
            }
#pragma unroll
            for (int off = 1; off < 16; off <<= 1) {
                apv = fmaxf(apv, __shfl_xor(apv, off, 64));
                anv = fminf(anv, __shfl_xor(anv, off, 64));
            }
            if (fr == 0) {
                atomicMax(&ap2[row0 + il], __float_as_uint(apv));
                atomicMin(&an2[row0 + il], __float_as_uint(anv));
            }
        }
    }
}

// ---------- Kernel 3: finalize loss + precision ----------
__global__ __launch_bounds__(256) void finalize_kernel(
    const unsigned* __restrict__ ap2, const unsigned* __restrict__ an2, float* __restrict__ out)
{
    const int t = threadIdx.x;
    float ls = 0.f, ps = 0.f;
    for (int i = t; i < N_ROWS; i += 256) {
        const float ap = sqrtf(__uint_as_float(ap2[i]));
        const float an = sqrtf(__uint_as_float(an2[i]));
        ls += fmaxf(MARGIN - an + ap, 0.f);
        ps += (an > ap) ? 1.f : 0.f;
    }
#pragma unroll
    for (int off = 32; off >= 1; off >>= 1) {
        ls += __shfl_down(ls, off, 64);
        ps += __shfl_down(ps, off, 64);
    }
    __shared__ float rl[4], rp[4];
    if ((t & 63) == 0) { rl[t >> 6] = ls; rp[t >> 6] = ps; }
    __syncthreads();
    if (t == 0) {
        out[0] = (rl[0] + rl[1] + rl[2] + rl[3]) * (1.f / N_ROWS);
        out[1] = (rp[0] + rp[1] + rp[2] + rp[3]) * (1.f / N_ROWS);
    }
}

extern "C" void kernel_launch(void* const* d_in, const int* in_sizes, int n_in,
                              void* d_out, int out_size, void* d_ws, size_t ws_size,
                              hipStream_t stream)
{
    const float* emb = (const float*)d_in[0];
    const int* lab = (const int*)d_in[1];
    float* out = (float*)d_out;

    char* ws = (char*)d_ws;
    u16* embB   = (u16*)ws;                                           // 16 MB
    float* xx   = (float*)(ws + (size_t)N_ROWS * D_K * 2);
    unsigned* ap2 = (unsigned*)(ws + (size_t)N_ROWS * D_K * 2 + N_ROWS * 4);
    unsigned* an2 = (unsigned*)(ws + (size_t)N_ROWS * D_K * 2 + 2 * (size_t)N_ROWS * 4);

    prep_kernel<<<N_ROWS, 256, 0, stream>>>(emb, embB, xx, ap2, an2);
    dim3 grid((N_ROWS / BM) * (N_ROWS / BM));   // 16*16 = 256 blocks, 1 per CU
    gram_reduce_kernel<<<grid, 512, 0, stream>>>(embB, xx, lab, ap2, an2);
    finalize_kernel<<<1, 256, 0, stream>>>(ap2, an2, out);
}